// Round 5
// baseline (309.321 us; speedup 1.0000x reference)
//
#include <hip/hip_runtime.h>
#include <hip/hip_bf16.h>
#include <stdint.h>

// causal_attention: B=8, C=128, N=4096, strict causal (j<i), fp32 I/O, [B][C][N].
// prep: Qt,Kt=[B][N][C] bf16 (LDS transpose, cvt_pk), Vb=[B][C][N] bf16. ws 24MB.
// attn: flash attention, 32x32x16 bf16 MFMA, swapped operands both sides
//       (S^T = K*Q^T, O^T = V^T*P^T -> q = lane&31 everywhere, lane-local
//       softmax state). QBLK=KVBLK=32; 4 waves = 4-way KV-tile parity; 1024
//       blocks (4/CU); Q hoisted to registers from global; double-buffered
//       global_load_lds staging w/ pre-swizzled source; defer-max (THR=8);
//       setprio around MFMA; 4-partial tree merge in reused LDS.

#define BATCH 8
#define CH    128
#define NN    4096
#define C2 0.12751745f   // log2(e)/sqrt(128)

typedef __attribute__((ext_vector_type(8))) short short8;
typedef __attribute__((ext_vector_type(4))) float f32x4;
typedef __attribute__((ext_vector_type(16))) float f32x16;
typedef __attribute__((ext_vector_type(2))) int v2i;

__device__ __forceinline__ void gload16(const void* g, void* l) {
  __builtin_amdgcn_global_load_lds(
      (const __attribute__((address_space(1))) void*)g,
      (__attribute__((address_space(3))) void*)l, 16, 0, 0);
}

__device__ __forceinline__ int pk_bf16(float lo, float hi) {
  int d;
  asm("v_cvt_pk_bf16_f32 %0, %1, %2" : "=v"(d) : "v"(lo), "v"(hi));
  return d;
}

__device__ __forceinline__ void plswap(int& a, int& b) {
  v2i r = __builtin_amdgcn_permlane32_swap(a, b, false, false);
  a = r[0]; b = r[1];
}

// ---------------- prep ------------------------------------------------------
// blocks 0..1023: transpose Q/K 64n x 128c tiles -> [B][N][C] bf16
// blocks 1024..2047: V fp32 -> bf16 passthrough
__global__ __launch_bounds__(256) void prep_kernel(
    const float* __restrict__ key, const float* __restrict__ mixin,
    const float* __restrict__ query,
    unsigned short* __restrict__ qt, unsigned short* __restrict__ kt,
    unsigned short* __restrict__ vb) {
  int bid = blockIdx.x;
  int tid = threadIdx.x;
  if (bid < 1024) {
    __shared__ float tlf[64 * 133];
    const float* src = (bid < 512) ? query : key;
    unsigned short* dst = (bid < 512) ? qt : kt;
    int b = (bid >> 6) & 7;
    int n0 = (bid & 63) * 64;
    const float* sb = src + (size_t)b * CH * NN;
    int nl = (tid & 15) * 4;
#pragma unroll
    for (int i = 0; i < 8; ++i) {
      int c = (tid >> 4) + i * 16;
      float4 v = *(const float4*)&sb[(size_t)c * NN + n0 + nl];
      tlf[(nl + 0) * 133 + c] = v.x;
      tlf[(nl + 1) * 133 + c] = v.y;
      tlf[(nl + 2) * 133 + c] = v.z;
      tlf[(nl + 3) * 133 + c] = v.w;
    }
    __syncthreads();
    unsigned short* db = dst + (size_t)(b * NN + n0) * CH;
    int c8 = (tid & 15) * 8;
#pragma unroll
    for (int i = 0; i < 4; ++i) {
      int n = (tid >> 4) + i * 16;
      const float* row = &tlf[n * 133 + c8];
      int4 o;
      o.x = pk_bf16(row[0], row[1]);
      o.y = pk_bf16(row[2], row[3]);
      o.z = pk_bf16(row[4], row[5]);
      o.w = pk_bf16(row[6], row[7]);
      *(int4*)&db[(size_t)n * CH + c8] = o;
    }
  } else {
    int id = bid - 1024;
    size_t base = (size_t)id * 4096 + tid * 4;
#pragma unroll
    for (int it = 0; it < 4; ++it) {
      size_t idx = base + (size_t)it * 1024;
      float4 v = *(const float4*)&mixin[idx];
      v2i o;
      o[0] = pk_bf16(v.x, v.y);
      o[1] = pk_bf16(v.z, v.w);
      *(v2i*)&vb[idx] = o;
    }
  }
}

// ---------------- attention -------------------------------------------------
// LDS: dbuf 2 x (K 8KB + V 8KB) = 32768; merge reuses it; ml at 33792..35839.
__global__ __launch_bounds__(256, 4) void attn_kernel(
    const unsigned short* __restrict__ qt, const unsigned short* __restrict__ kt,
    const unsigned short* __restrict__ vb, float* __restrict__ out) {
  __shared__ __align__(16) unsigned char smem[35840];
  int tid = threadIdx.x;
  int wid = tid >> 6;      // 4-way KV-tile parity
  int lane = tid & 63;
  int l31 = lane & 31;
  int hi = lane >> 5;

  int gid = blockIdx.x;
  int b = gid & 7;                           // batch -> XCD (K/V fit XCD L2)
  int i = gid >> 3;                          // 0..127
  int qb = (i < 64) ? (127 - i) : (i - 64);  // per-CU tile-count balance
  int q0 = qb * 32;
  int ntiles = qb + 1;

  const unsigned char* Qb = (const unsigned char*)(qt + (size_t)b * NN * CH);
  const unsigned char* Kb = (const unsigned char*)(kt + (size_t)b * NN * CH);
  const unsigned char* Vp = (const unsigned char*)(vb + (size_t)b * CH * NN);

  // staging source offsets, pre-swizzled (gload_lds dest is linear: tid*16)
  int kg[2], vg[2];
#pragma unroll
  for (int i2 = 0; i2 < 2; ++i2) {
    int row = i2 * 16 + (tid >> 4);
    kg[i2] = row * 256 + (((tid & 15) ^ (row & 7)) << 4);
    int c = i2 * 64 + (tid >> 2);
    vg[i2] = c * 8192 + (((tid & 3) ^ (c & 3)) << 4);
  }

  // Q fragments direct from global (B operand: col=q=l31, 8 c per frag)
  short8 qf[8];
#pragma unroll
  for (int cs = 0; cs < 8; ++cs)
    qf[cs] = *(const short8*)&Qb[(size_t)(q0 + l31) * 256 + cs * 32 + hi * 16];

  // prologue: stage tile 0 into buf0
#pragma unroll
  for (int i2 = 0; i2 < 2; ++i2) {
    gload16(Kb + kg[i2], smem + i2 * 4096 + tid * 16);
    gload16(Vp + vg[i2], smem + 8192 + i2 * 4096 + tid * 16);
  }
  __syncthreads();

  f32x16 O[4];
#pragma unroll
  for (int ct = 0; ct < 4; ++ct)
#pragma unroll
    for (int r = 0; r < 16; ++r) O[ct][r] = 0.f;
  float m_run = -1e30f, l_run = 0.f;

  for (int t = 0; t < ntiles; ++t) {
    if (t + 1 < ntiles) {  // stage next tile (all waves help)
      unsigned char* nb = smem + ((t + 1) & 1) * 16384;
      const unsigned char* Ks = Kb + (size_t)(t + 1) * 8192;
      const unsigned char* Vs = Vp + (size_t)(t + 1) * 64;
#pragma unroll
      for (int i2 = 0; i2 < 2; ++i2) {
        gload16(Ks + kg[i2], nb + i2 * 4096 + tid * 16);
        gload16(Vs + vg[i2], nb + 8192 + i2 * 4096 + tid * 16);
      }
    }
    if ((t & 3) == wid) {
      const unsigned char* bk = smem + (t & 1) * 16384;
      const unsigned char* bv = bk + 8192;
      // S^T = K * Q^T : D col = q = l31, row k = crow(r,hi)
      f32x16 S;
#pragma unroll
      for (int r = 0; r < 16; ++r) S[r] = 0.f;
      __builtin_amdgcn_s_setprio(1);
#pragma unroll
      for (int cs = 0; cs < 8; ++cs) {
        short8 kf = *(const short8*)&bk[l31 * 256 +
                                        ((cs * 32 + hi * 16) ^ ((l31 & 7) << 4))];
        S = __builtin_amdgcn_mfma_f32_32x32x16_bf16(kf, qf[cs], S, 0, 0, 0);
      }
      __builtin_amdgcn_s_setprio(0);
      if (t == qb) {  // diagonal: strict causal mask k >= q
#pragma unroll
        for (int r = 0; r < 16; ++r) {
          int kl = (r & 3) + 8 * (r >> 2) + 4 * hi;
          if (kl >= l31) S[r] = -__builtin_inff();
        }
      }
      // online softmax (lane-local, + lane^32 combine), defer-max THR=8
      float mx = S[0];
#pragma unroll
      for (int r = 1; r < 16; ++r) mx = fmaxf(mx, S[r]);
      mx = fmaxf(mx, __shfl_xor(mx, 32));
      bool skip = __all(mx - m_run <= 8.0f);
      float mn, al;
      if (skip) { mn = m_run; al = 1.0f; }
      else { mn = fmaxf(m_run, mx); al = __builtin_amdgcn_exp2f((m_run - mn) * C2); m_run = mn; }
      float rs = 0.f;
#pragma unroll
      for (int r = 0; r < 16; ++r) {
        S[r] = __builtin_amdgcn_exp2f((S[r] - mn) * C2);
        rs += S[r];
      }
      rs += __shfl_xor(rs, 32);
      l_run = l_run * al + rs;
      if (!skip) {
#pragma unroll
        for (int ct = 0; ct < 4; ++ct)
#pragma unroll
          for (int r = 0; r < 16; ++r) O[ct][r] *= al;
      }
      // P repack (cvt_pk + permlane32_swap) -> B operand; O^T = V^T * P^T
#pragma unroll
      for (int ks = 0; ks < 2; ++ks) {
        int b8 = ks * 8;
        int cA = pk_bf16(S[b8 + 0], S[b8 + 1]);
        int cB = pk_bf16(S[b8 + 2], S[b8 + 3]);
        int cC = pk_bf16(S[b8 + 4], S[b8 + 5]);
        int cD = pk_bf16(S[b8 + 6], S[b8 + 7]);
        plswap(cA, cC);
        plswap(cB, cD);
        union { int w[4]; short8 s; } pu;
        pu.w[0] = cA; pu.w[1] = cB; pu.w[2] = cC; pu.w[3] = cD;
        int vwo = ks * 32 + hi * 16;
        __builtin_amdgcn_s_setprio(1);
#pragma unroll
        for (int ct = 0; ct < 4; ++ct) {
          int c = ct * 32 + l31;
          short8 vf = *(const short8*)&bv[c * 64 + (vwo ^ ((c & 3) << 4))];
          O[ct] = __builtin_amdgcn_mfma_f32_32x32x16_bf16(vf, pu.s, O[ct], 0, 0, 0);
        }
        __builtin_amdgcn_s_setprio(0);
      }
    }
    __syncthreads();
  }

  // ---- 4-partial tree merge (reuse dbuf LDS) ----
  // O[ct][r]: c = ct*32 + crow(r,hi), q = q0 + l31; (m,l) per-lane.
  float* mlb = (float*)(smem + 33792);
  unsigned char* regA = smem;
  unsigned char* regB = smem + 16896;
  mlb[(wid * 64 + lane) * 2 + 0] = m_run;
  mlb[(wid * 64 + lane) * 2 + 1] = l_run;
  if (wid & 1) {  // waves 1,3 publish
    unsigned char* rg = (wid == 1) ? regA : regB;
#pragma unroll
    for (int ct = 0; ct < 4; ++ct)
#pragma unroll
      for (int i4 = 0; i4 < 4; ++i4) {
        f32x4 v = {O[ct][i4 * 4 + 0], O[ct][i4 * 4 + 1],
                   O[ct][i4 * 4 + 2], O[ct][i4 * 4 + 3]};
        *(f32x4*)&rg[lane * 264 + ct * 64 + i4 * 16] = v;
      }
  }
  __syncthreads();
  if (!(wid & 1)) {  // waves 0,2 merge partners
    unsigned char* rg = (wid == 0) ? regA : regB;
    int sw = wid + 1;
    float m1 = mlb[(sw * 64 + lane) * 2 + 0];
    float l1 = mlb[(sw * 64 + lane) * 2 + 1];
    float ms = fmaxf(m_run, m1);
    float a0 = __builtin_amdgcn_exp2f((m_run - ms) * C2);
    float a1 = __builtin_amdgcn_exp2f((m1 - ms) * C2);
#pragma unroll
    for (int ct = 0; ct < 4; ++ct)
#pragma unroll
      for (int i4 = 0; i4 < 4; ++i4) {
        f32x4 o1 = *(const f32x4*)&rg[lane * 264 + ct * 64 + i4 * 16];
#pragma unroll
        for (int j = 0; j < 4; ++j)
          O[ct][i4 * 4 + j] = O[ct][i4 * 4 + j] * a0 + o1[j] * a1;
      }
    m_run = ms;
    l_run = l_run * a0 + l1 * a1;
  }
  if (wid == 2) {  // publish merged {2,3}
#pragma unroll
    for (int ct = 0; ct < 4; ++ct)
#pragma unroll
      for (int i4 = 0; i4 < 4; ++i4) {
        f32x4 v = {O[ct][i4 * 4 + 0], O[ct][i4 * 4 + 1],
                   O[ct][i4 * 4 + 2], O[ct][i4 * 4 + 3]};
        *(f32x4*)&regB[lane * 264 + ct * 64 + i4 * 16] = v;
      }
    mlb[(2 * 64 + lane) * 2 + 0] = m_run;
    mlb[(2 * 64 + lane) * 2 + 1] = l_run;
  }
  __syncthreads();
  if (wid == 0) {  // final merge + divide + store
    float m1 = mlb[(2 * 64 + lane) * 2 + 0];
    float l1 = mlb[(2 * 64 + lane) * 2 + 1];
    float ms = fmaxf(m_run, m1);
    float a0 = __builtin_amdgcn_exp2f((m_run - ms) * C2);
    float a1 = __builtin_amdgcn_exp2f((m1 - ms) * C2);
    float lt = l_run * a0 + l1 * a1;
    float rd = 1.0f / (lt + 1e-6f);
    int q = q0 + l31;
#pragma unroll
    for (int ct = 0; ct < 4; ++ct)
#pragma unroll
      for (int i4 = 0; i4 < 4; ++i4) {
        f32x4 o1 = *(const f32x4*)&regB[lane * 264 + ct * 64 + i4 * 16];
#pragma unroll
        for (int j = 0; j < 4; ++j) {
          int r = i4 * 4 + j;
          int c = ct * 32 + (r & 3) + 8 * (r >> 2) + 4 * hi;
          out[(size_t)(b * CH + c) * NN + q] = (O[ct][r] * a0 + o1[j] * a1) * rd;
        }
      }
  }
}

extern "C" void kernel_launch(void* const* d_in, const int* in_sizes, int n_in,
                              void* d_out, int out_size, void* d_ws, size_t ws_size,
                              hipStream_t stream) {
  const float* key = (const float*)d_in[0];
  const float* mixin = (const float*)d_in[1];
  const float* query = (const float*)d_in[2];
  float* out = (float*)d_out;

  unsigned short* qtp = (unsigned short*)d_ws;
  unsigned short* ktp = qtp + (size_t)BATCH * NN * CH;
  unsigned short* vbp = ktp + (size_t)BATCH * NN * CH;

  prep_kernel<<<2048, 256, 0, stream>>>(key, mixin, query, qtp, ktp, vbp);
  attn_kernel<<<1024, 256, 0, stream>>>(qtp, ktp, vbp, out);
}